// Round 7
// baseline (367.303 us; speedup 1.0000x reference)
//
#include <hip/hip_runtime.h>
#include <hip/hip_bf16.h>
#include <stdint.h>

#define TOTAL 4096
#define EMB 384
#define MD 32
#define NDOCS (TOTAL - 1 - MD)   // 4063
#define LN_EPS 1e-5f
#define NEGF (-1e30f)

typedef __hip_bfloat16 bf16;
typedef unsigned short ushort_t;
typedef __attribute__((ext_vector_type(8))) short short8;
typedef __attribute__((ext_vector_type(4))) float f32x4;
typedef __attribute__((ext_vector_type(2))) float f32x2;

// Dual-dtype load: inputs may be stored bf16 or fp32; isbf selects at runtime.
__device__ __forceinline__ float ldf(const void* p, int i, int isbf) {
    return isbf ? __bfloat162float(((const bf16*)p)[i]) : ((const float*)p)[i];
}

// round-half-up f32 -> bf16 bits
__device__ __forceinline__ unsigned f2bf(float x) {
    return (__float_as_uint(x) + 0x8000u) >> 16;
}

// order-preserving float<->uint for atomicMax over signed floats
__device__ __forceinline__ unsigned fenc(float f) {
    unsigned u = __float_as_uint(f);
    return (u >> 31) ? ~u : (u | 0x80000000u);
}
__device__ __forceinline__ float fdec(unsigned k) {
    return __uint_as_float((k & 0x80000000u) ? (k & 0x7FFFFFFFu) : ~k);
}

// ---------------- adj -> bitmask; + dtype detect + dmax init + weight transpose -------
// R6 lesson: 4096 tiny blocks (~300ns work each) were dispatch-rate-bound — CP can't
// feed 256 CUs, Occupancy 30%, 78us. Now 512 blocks x 8 adj rows each (identical
// ballot loop per row); transpose is a grid-stride loop; q-row projection uses 4
// independent FMA chains + unroll (R6's sequential chain was a one-block straggler).
// Weights packed float4-per-column: T[(d>>2)*1024 + c*4 + (d&3)].
#define TRTOT (EMB * 256 + 2 * 65536 + 514 * 256)   // 360960 transpose elements
__global__ __launch_bounds__(256) void k_adjmask(
        const int* adj, unsigned long long* maskb,
        const uint16_t* embp, int* flag, unsigned* dmaxu,
        const void* proj_w, const void* proj_b, const void* gat_W,
        const void* fusion_w,
        float* projT, float* gatT, float* fwT, float* qrow) {
    __shared__ int red[4];
    __shared__ float qred2[4];
    int bid = blockIdx.x, t = threadIdx.x;
    int w = t >> 6, l = t & 63;
    // ---- 8 adj rows -> bitmasks ----
#pragma unroll
    for (int r8 = 0; r8 < 8; r8++) {
        int i = bid * 8 + r8;
        for (int c = w; c < 64; c += 4) {
            int a = adj[(size_t)i * TOTAL + c * 64 + l];
            unsigned long long m = __ballot(a != 0);
            if (l == 0) maskb[i * 64 + c] = m;
        }
    }
    if (bid == 0) {                                // init 2 layers x 64 slots x 16
        for (int idx = t; idx < 2048; idx += 256) dmaxu[idx] = 0x007FFFFFu;  // fenc(-inf)
    }
    // ---- dtype detect (every block, deterministic) ----
    int cnt = 0;
    for (int k = t; k < 4096; k += 256) {
        uint16_t wd = embp[2 * k];
        int e = (wd >> 7) & 0xFF;
        if (e >= 100 && e <= 140) cnt++;
    }
    for (int o = 32; o > 0; o >>= 1) cnt += __shfl_down(cnt, o);
    if ((t & 63) == 0) red[t >> 6] = cnt;
    __syncthreads();
    int isbf = (red[0] + red[1] + red[2] + red[3] > 2048) ? 1 : 0;
    if (bid == 0 && t == 0) flag[0] = isbf;
    // ---- weight transpose (grid-stride over all 360960 elements) ----
    for (int idx = bid * 256 + t; idx < TRTOT; idx += 512 * 256) {
        if (idx < EMB * 256) {
            int d = idx >> 8, c = idx & 255;
            projT[(d >> 2) * 1024 + c * 4 + (d & 3)] = ldf(proj_w, c * EMB + d, isbf);
        } else if (idx < EMB * 256 + 2 * 65536) {
            int r = idx - EMB * 256;
            int ll = r >> 16, rem = r & 65535;
            int d = rem >> 8, c = rem & 255;
            gatT[ll * 65536 + (d >> 2) * 1024 + c * 4 + (d & 3)] =
                ldf(gat_W, ll * 65536 + c * 256 + d, isbf);
        } else {
            int r = idx - (EMB * 256 + 2 * 65536);
            int j = r >> 8, c = r & 255;
            fwT[(j >> 2) * 1024 + c * 4 + (j & 3)] = ldf(fusion_w, c * 514 + j, isbf);
        }
    }
    // ---- q-row projection (last block): 4 independent chains, loads batched ----
    if (bid == 511) {
        const void* embv = (const void*)embp;
        float p0 = 0.f, p1 = 0.f, p2 = 0.f, p3 = 0.f;
#pragma unroll 4
        for (int d = 0; d < EMB; d += 4) {
            float e0 = ldf(embv, d, isbf),     e1 = ldf(embv, d + 1, isbf);
            float e2 = ldf(embv, d + 2, isbf), e3 = ldf(embv, d + 3, isbf);
            p0 = fmaf(e0, ldf(proj_w, (size_t)t * EMB + d, isbf), p0);
            p1 = fmaf(e1, ldf(proj_w, (size_t)t * EMB + d + 1, isbf), p1);
            p2 = fmaf(e2, ldf(proj_w, (size_t)t * EMB + d + 2, isbf), p2);
            p3 = fmaf(e3, ldf(proj_w, (size_t)t * EMB + d + 3, isbf), p3);
        }
        float accq = (p0 + p2) + (p1 + p3);
        float qv = fmaxf(accq + ldf(proj_b, t, isbf), 0.f);
        qrow[t] = qv;
        float a = qv * qv;
        for (int o = 32; o > 0; o >>= 1) a += __shfl_down(a, o);
        if ((t & 63) == 0) qred2[t >> 6] = a;
        __syncthreads();
        if (t == 0) qrow[256] = sqrtf(qred2[0] + qred2[1] + qred2[2] + qred2[3]) + 1e-8f;
    }
}

// ---------------- [proj+cos | read h] + LN + Wh GEMM + src/dst, 512 threads -----------
// Mapping (R5→R6): wave w8 = row owner (8 waves = 8 rows) AND d-split group;
// lane l = col-within-head; thread owns 4 cols {l, l+64, l+128, l+192}. Each
// broadcast x-read feeds 16 FMAs; weights stream once per block. Split-K partials
// exchanged via xpart (b32 stride-1, conflict-free), reduced in 2 passes of 4 rows.
// Row==wave makes cos/LN/src/dst reductions wave-local.
#define LR 8
__global__ __launch_bounds__(512) void k_lnwh(
        const void* emb, const void* proj_b, const float* projT,
        float* h, const float* gatT, const void* ln_scale, const void* ln_bias,
        const void* gat_a, ushort_t* whswz, float* srcb, unsigned* d12g,
        unsigned* dmaxu, int layer, const int* flagp, const float* qrow) {
    __shared__ float embs[8][EMB];          // 12KB (layer 0 only)
    __shared__ float xs[8][256];            // 8KB
    __shared__ float xpart[8][4][256];      // 32KB split-K partials (2-pass reuse)
    int isbf = flagp[0];
    int t5 = threadIdx.x;
    int w8 = t5 >> 6;                       // wave = row = d-group
    int l = t5 & 63;                        // lane = col-within-head
    int i0 = blockIdx.x * LR;
    int myrow = i0 + w8;
    float hv[4];
    if (layer == 0) {
        for (int idx = t5; idx < 8 * EMB; idx += 512) {
            int r = idx / EMB, d = idx % EMB;
            embs[r][d] = ldf(emb, (i0 + r) * EMB + d, isbf);
        }
        __syncthreads();
        // ---- proj producer: k4 in [w8*12, w8*12+12), 8 rows x 4 cols ----
        const float4* pT4 = (const float4*)projT;
        float ap[8][4];
#pragma unroll
        for (int r = 0; r < 8; r++)
#pragma unroll
            for (int cc = 0; cc < 4; cc++) ap[r][cc] = 0.f;
        for (int s = 0; s < 12; s++) {
            int k4 = w8 * 12 + s;
            float4 wv[4];
#pragma unroll
            for (int cc = 0; cc < 4; cc++) wv[cc] = pT4[k4 * 256 + cc * 64 + l];
#pragma unroll
            for (int r = 0; r < 8; r++) {
                float4 x = *(const float4*)&embs[r][k4 * 4];
#pragma unroll
                for (int cc = 0; cc < 4; cc++) {
                    ap[r][cc] = fmaf(x.x, wv[cc].x, ap[r][cc]);
                    ap[r][cc] = fmaf(x.y, wv[cc].y, ap[r][cc]);
                    ap[r][cc] = fmaf(x.z, wv[cc].z, ap[r][cc]);
                    ap[r][cc] = fmaf(x.w, wv[cc].w, ap[r][cc]);
                }
            }
        }
        // ---- split-K reduce, 2 passes of 4 rows ----
#pragma unroll
        for (int r = 0; r < 4; r++)
#pragma unroll
            for (int cc = 0; cc < 4; cc++) xpart[w8][r][cc * 64 + l] = ap[r][cc];
        __syncthreads();
        float bias[4];
#pragma unroll
        for (int cc = 0; cc < 4; cc++) bias[cc] = ldf(proj_b, cc * 64 + l, isbf);
        if (w8 < 4) {
#pragma unroll
            for (int cc = 0; cc < 4; cc++) {
                float s = 0.f;
#pragma unroll
                for (int g = 0; g < 8; g++) s += xpart[g][w8][cc * 64 + l];
                hv[cc] = fmaxf(s + bias[cc], 0.f);
            }
        }
        __syncthreads();
#pragma unroll
        for (int r = 4; r < 8; r++)
#pragma unroll
            for (int cc = 0; cc < 4; cc++) xpart[w8][r - 4][cc * 64 + l] = ap[r][cc];
        __syncthreads();
        if (w8 >= 4) {
#pragma unroll
            for (int cc = 0; cc < 4; cc++) {
                float s = 0.f;
#pragma unroll
                for (int g = 0; g < 8; g++) s += xpart[g][w8 - 4][cc * 64 + l];
                hv[cc] = fmaxf(s + bias[cc], 0.f);
            }
        }
        // ---- cos-update (qrow precomputed): s += 0.8*cos(q,s)*q, doc rows only ----
        if (myrow >= 1 + MD) {
            float qv[4];
#pragma unroll
            for (int cc = 0; cc < 4; cc++) qv[cc] = qrow[cc * 64 + l];
            float b = 0.f, c = 0.f;
#pragma unroll
            for (int cc = 0; cc < 4; cc++) {
                b = fmaf(hv[cc], hv[cc], b);
                c = fmaf(qv[cc], hv[cc], c);
            }
            for (int o = 32; o > 0; o >>= 1) { b += __shfl_xor(b, o); c += __shfl_xor(c, o); }
            float qn = qrow[256];
            float k = 0.8f * (c / (qn * (sqrtf(b) + 1e-8f)));
#pragma unroll
            for (int cc = 0; cc < 4; cc++) hv[cc] += k * qv[cc];
        }
#pragma unroll
        for (int cc = 0; cc < 4; cc++) h[(size_t)myrow * 256 + cc * 64 + l] = hv[cc];
    } else {
#pragma unroll
        for (int cc = 0; cc < 4; cc++) hv[cc] = h[(size_t)myrow * 256 + cc * 64 + l];
    }
    // ---- layernorm (wave-local: wave == row) ----
    {
        float a = 0.f, b2 = 0.f;
#pragma unroll
        for (int cc = 0; cc < 4; cc++) { a += hv[cc]; b2 = fmaf(hv[cc], hv[cc], b2); }
        for (int o = 32; o > 0; o >>= 1) { a += __shfl_xor(a, o); b2 += __shfl_xor(b2, o); }
        float mu = a * (1.f / 256.f);
        float var = b2 * (1.f / 256.f) - mu * mu;
        float rs = rsqrtf(var + LN_EPS);
#pragma unroll
        for (int cc = 0; cc < 4; cc++) {
            float sc = ldf(ln_scale, layer * 256 + cc * 64 + l, isbf);
            float lb = ldf(ln_bias, layer * 256 + cc * 64 + l, isbf);
            xs[w8][cc * 64 + l] = (hv[cc] - mu) * rs * sc + lb;
        }
    }
    __syncthreads();
    // ---- Wh producer: k4 in [w8*8, w8*8+8) ----
    const float4* gT4 = (const float4*)(gatT + layer * 65536);
    float aw[8][4];
#pragma unroll
    for (int r = 0; r < 8; r++)
#pragma unroll
        for (int cc = 0; cc < 4; cc++) aw[r][cc] = 0.f;
    for (int s = 0; s < 8; s++) {
        int k4 = w8 * 8 + s;
        float4 wv[4];
#pragma unroll
        for (int cc = 0; cc < 4; cc++) wv[cc] = gT4[k4 * 256 + cc * 64 + l];
#pragma unroll
        for (int r = 0; r < 8; r++) {
            float4 x = *(const float4*)&xs[r][k4 * 4];
#pragma unroll
            for (int cc = 0; cc < 4; cc++) {
                aw[r][cc] = fmaf(x.x, wv[cc].x, aw[r][cc]);
                aw[r][cc] = fmaf(x.y, wv[cc].y, aw[r][cc]);
                aw[r][cc] = fmaf(x.z, wv[cc].z, aw[r][cc]);
                aw[r][cc] = fmaf(x.w, wv[cc].w, aw[r][cc]);
            }
        }
    }
#pragma unroll
    for (int r = 0; r < 4; r++)
#pragma unroll
        for (int cc = 0; cc < 4; cc++) xpart[w8][r][cc * 64 + l] = aw[r][cc];
    __syncthreads();
    float acc2[4];
    if (w8 < 4) {
#pragma unroll
        for (int cc = 0; cc < 4; cc++) {
            float s = 0.f;
#pragma unroll
            for (int g = 0; g < 8; g++) s += xpart[g][w8][cc * 64 + l];
            acc2[cc] = s;
        }
    }
    __syncthreads();
#pragma unroll
    for (int r = 4; r < 8; r++)
#pragma unroll
        for (int cc = 0; cc < 4; cc++) xpart[w8][r - 4][cc * 64 + l] = aw[r][cc];
    __syncthreads();
    if (w8 >= 4) {
#pragma unroll
        for (int cc = 0; cc < 4; cc++) {
            float s = 0.f;
#pragma unroll
            for (int g = 0; g < 8; g++) s += xpart[g][w8 - 4][cc * 64 + l];
            acc2[cc] = s;
        }
    }
    // ---- whswz store + src/dst reductions + dmax (col cc*64+l == head cc, lane l) ----
#pragma unroll
    for (int cc = 0; cc < 4; cc++) {
        int col = cc * 64 + l;
        int off = (myrow >> 6) * 16384 + (col >> 6) * 4096 + ((myrow >> 3) & 7) * 512 +
                  ((col >> 4) & 3) * 128 + (col & 15) * 8 + (myrow & 7);
        whswz[off] = (ushort_t)f2bf(acc2[cc]);
    }
    float sv[4], dv[4];
#pragma unroll
    for (int cc = 0; cc < 4; cc++) {
        float av1 = ldf(gat_a, layer * 512 + cc * 128 + l, isbf);
        float av2 = ldf(gat_a, layer * 512 + cc * 128 + 64 + l, isbf);
        sv[cc] = acc2[cc] * av1;
        dv[cc] = acc2[cc] * av2;
    }
    for (int o = 32; o > 0; o >>= 1) {
#pragma unroll
        for (int cc = 0; cc < 4; cc++) {
            sv[cc] += __shfl_down(sv[cc], o);
            dv[cc] += __shfl_down(dv[cc], o);
        }
    }
    if (l == 0) {
        const float LOG2E = 1.44269504f;
#pragma unroll
        for (int cc = 0; cc < 4; cc++) {
            srcb[cc * 4096 + myrow] = sv[cc];
            float D1 = exp2f(dv[cc] * LOG2E), D2 = exp2f(0.2f * dv[cc] * LOG2E);
            d12g[cc * 4096 + myrow] = (f2bf(D2) << 16) | f2bf(D1);
            atomicMax(&dmaxu[(blockIdx.x & 63) * 16 + cc], fenc(dv[cc]));
        }
    }
}

// ---------------- PV via MFMA, full-j accumulation + FUSED epilogue -------------------
#define TI 16
__global__ __launch_bounds__(512) void k_pv(const ushort_t* whswz, const float* srcb,
                                            const unsigned* dmaxu, const unsigned* d12g,
                                            const unsigned long long* maskb, float* h) {
    __shared__ unsigned long long mbs[16 * 66];            // masks: 16 rows x 64 words
    __shared__ __align__(16) f32x4 accsh[16 * 64];         // 16KB cross-kq reduce
    __shared__ __align__(16) float lsh[4][4][4];           // [head][quad][rr] kq1 rowsums
    __shared__ float srcs[64];
    __shared__ float dmx[4];
    __shared__ unsigned mlut[4];
    int t = threadIdx.x;
    int W = t >> 6, lane = t & 63;
    int hH = W & 3, kq = W >> 2;
    int quad = lane >> 4, c16 = lane & 15;
    int i0 = blockIdx.x * TI;
    if (t < 4) mlut[t] = (t & 1 ? 0x0000FFFFu : 0u) | (t & 2 ? 0xFFFF0000u : 0u);
    if (t < 256) {                                 // wave w reduces head w's 64 dmax slots
        int hh = t >> 6, sl = t & 63;
        float v = fdec(dmaxu[sl * 16 + hh]);
        for (int o = 32; o > 0; o >>= 1) v = fmaxf(v, __shfl_xor(v, o));
        if (sl == 0) dmx[hh] = v;
    }
    for (int idx = t; idx < 16 * 64; idx += 512) {
        int r = idx >> 6, wd = idx & 63;
        mbs[r * 66 + wd] = maskb[(size_t)(i0 + r) * 64 + wd];
    }
    if (t < 64) srcs[t] = srcb[(t >> 4) * 4096 + i0 + (t & 15)];
    __syncthreads();
    const float LOG2E = 1.44269504f;
    float dm = dmx[hH];
    float src = srcs[hH * 16 + c16];
    float sd = src + dm;
    float rce = -fmaxf(sd, 0.2f * sd);             // -mhat >= true masked max
    float E1 = exp2f((src + rce) * LOG2E);
    float E2 = exp2f((0.2f * src + rce) * LOG2E);
    f32x4 acc[4];
    f32x4 accl = (f32x4){0.f, 0.f, 0.f, 0.f};
#pragma unroll
    for (int ct = 0; ct < 4; ct++) acc[ct] = (f32x4){0.f, 0.f, 0.f, 0.f};
    uint4 onesu;                                   // B ones-column frag (col c16==0)
    unsigned os = (c16 == 0) ? 0x3F803F80u : 0u;
    onesu.x = os; onesu.y = os; onesu.z = os; onesu.w = os;
    short8 bfones = __builtin_bit_cast(short8, onesu);
    const uint4* g4 = (const uint4*)whswz;
    const uint4* d4 = (const uint4*)d12g;
    size_t b0 = (size_t)hH * 512 + (size_t)(kq * 4 + quad) * 64 + c16;
    int dbase = hH * 1024, d0i = kq * 8 + quad * 2;   // uint4 units
    uint4 bA0 = g4[b0],        bA1 = g4[b0 + 16],        bA2 = g4[b0 + 32],        bA3 = g4[b0 + 48];
    uint4 bB0 = g4[b0 + 2048], bB1 = g4[b0 + 2048 + 16], bB2 = g4[b0 + 2048 + 32], bB3 = g4[b0 + 2048 + 48];
    uint4 dA0 = d4[dbase + d0i],      dA1 = d4[dbase + d0i + 1];
    uint4 dB0 = d4[dbase + 16 + d0i], dB1 = d4[dbase + 16 + d0i + 1];
    auto pvstep = [&](uint4& B0, uint4& B1, uint4& B2, uint4& B3,
                      uint4& DD0, uint4& DD1, int s) {
        uint4 bc0 = B0, bc1 = B1, bc2 = B2, bc3 = B3;
        uint4 dc0 = DD0, dc1 = DD1;
        if (s < 62) {                              // refill this slot with step s+2
            size_t bs = b0 + (size_t)(s + 2) * 2048;
            B0 = g4[bs]; B1 = g4[bs + 16]; B2 = g4[bs + 32]; B3 = g4[bs + 48];
            int di = dbase + (s + 2) * 16 + d0i;
            DD0 = d4[di]; DD1 = d4[di + 1];
        }
        unsigned mby = (unsigned)(mbs[c16 * 66 + s] >> (kq * 32 + quad * 8)) & 0xFFu;
        unsigned dw[8] = {dc0.x, dc0.y, dc0.z, dc0.w, dc1.x, dc1.y, dc1.z, dc1.w};
        unsigned pu[4];
#pragma unroll
        for (int q = 0; q < 4; q++) {
            unsigned a = dw[2 * q], b = dw[2 * q + 1];
            f32x2 D1 = (f32x2){__uint_as_float(a << 16), __uint_as_float(b << 16)};
            f32x2 D2 = (f32x2){__uint_as_float(a & 0xFFFF0000u), __uint_as_float(b & 0xFFFF0000u)};
            f32x2 v1 = D1 * E1;
            f32x2 v2 = D2 * E2;
            f32x2 m = __builtin_elementwise_max(v1, v2);
            unsigned v = ((__float_as_uint(m.x) + 0x8000u) >> 16) |
                         ((__float_as_uint(m.y) + 0x8000u) & 0xFFFF0000u);
            pu[q] = v & mlut[(mby >> (2 * q)) & 3u];
        }
        uint4 afu;
        afu.x = pu[0]; afu.y = pu[1]; afu.z = pu[2]; afu.w = pu[3];
        short8 af = __builtin_bit_cast(short8, afu);
        acc[0] = __builtin_amdgcn_mfma_f32_16x16x32_bf16(af, __builtin_bit_cast(short8, bc0), acc[0], 0, 0, 0);
        acc[1] = __builtin_amdgcn_mfma_f32_16x16x32_bf16(af, __builtin_bit_cast(short8, bc1), acc[1], 0, 0, 0);
        acc[2] = __builtin_amdgcn_mfma_f32_16x16x32_bf16(af, __builtin_bit_cast(short8, bc2), acc[2], 0, 0, 0);
        acc[3] = __builtin_amdgcn_mfma_f32_16x16x32_bf16(af, __builtin_bit_cast(short8, bc3), acc[3], 0, 0, 0);
        accl = __builtin_amdgcn_mfma_f32_16x16x32_bf16(af, bfones, accl, 0, 0, 0);
    };
    for (int sp = 0; sp < 32; sp++) {
        pvstep(bA0, bA1, bA2, bA3, dA0, dA1, 2 * sp);
        pvstep(bB0, bB1, bB2, bB3, dB0, dB1, 2 * sp + 1);
    }
    __syncthreads();
    if (kq == 1) {
#pragma unroll
        for (int ct = 0; ct < 4; ct++)
            accsh[(hH * 4 + ct) * 64 + lane] = acc[ct];
        if (c16 == 0) *(f32x4*)&lsh[hH][quad][0] = accl;
    }
    __syncthreads();
    if (kq == 0) {
        float ls[4];
#pragma unroll
        for (int rr = 0; rr < 4; rr++)
            ls[rr] = __shfl(accl[rr], quad * 16) + lsh[hH][quad][rr];
#pragma unroll
        for (int ct = 0; ct < 4; ct++) {
            f32x4 o = acc[ct] + accsh[(hH * 4 + ct) * 64 + lane];
#pragma unroll
            for (int rr = 0; rr < 4; rr++) {       // D: col=lane&15, row=quad*4+rr
                int row = i0 + quad * 4 + rr;
                size_t idx = (size_t)row * 256 + hH * 64 + ct * 16 + c16;
                float hn = 0.5f * fmaxf(o[rr] / ls[rr], 0.f) + 0.5f * h[idx];
                h[idx] = hn;
            }
        }
    }
}

// ---------------- scores + cos from final h (wave-per-row) ----------------------------
__global__ __launch_bounds__(256) void k_scores(const float* h, float* scoresv, float* cosv,
                                                float* swp) {
    int t = threadIdx.x, W = t >> 6, lane = t & 63;
    const float4* h4 = (const float4*)h;
    int gw = blockIdx.x * 4 + W;
    float4 q4 = h4[lane];                          // final q row
    float a = q4.x * q4.x + q4.y * q4.y + q4.z * q4.z + q4.w * q4.w;
    for (int o = 32; o > 0; o >>= 1) a += __shfl_xor(a, o);
    float qn = sqrtf(a) + 1e-8f;
    float mw = NEGF, sw = 0.f;
    for (int n = gw; n < NDOCS; n += 1024) {
        float4 s4 = h4[(size_t)(1 + MD + n) * 64 + lane];
        float b = s4.x * s4.x + s4.y * s4.y + s4.z * s4.z + s4.w * s4.w;
        float c = q4.x * s4.x + q4.y * s4.y + q4.z * s4.z + q4.w * s4.w;
        for (int o = 32; o > 0; o >>= 1) { b += __shfl_xor(b, o); c += __shfl_xor(c, o); }
        float sc = c * (1.f / 16.f);               // wave-uniform (full butterfly)
        if (lane == 0) {
            scoresv[n] = sc;
            cosv[n] = c / (qn * (sqrtf(b) + 1e-8f));
        }
        float mn = fmaxf(mw, sc);
        sw = sw * __expf(mw - mn) + __expf(sc - mn);
        mw = mn;
    }
    if (lane == 0) { swp[2 * gw] = mw; swp[2 * gw + 1] = sw; }
}

// ---------------- fused softmax-reduce + feature GEMM + output ------------------------
#define TN 8
__global__ __launch_bounds__(256) void k_fusion(const float* h,
                                                const float* scoresv, const float* swp,
                                                const float* cosv,
                                                const float* fwT, const void* fusion_b,
                                                const void* out_w, const void* out_bp,
                                                void* outv, const int* flagp) {
    __shared__ float feats2[514][TN];
    __shared__ float qhs[256];
    __shared__ float red[TN][4];
    __shared__ float reds[2][4];
    __shared__ float aws[TN];
    int isbf = flagp[0];
    int t = threadIdx.x;
    int n0 = blockIdx.x * TN;
    qhs[t] = h[t];                                 // final q row
    // reduce the 1024 per-wave online-softmax partials -> global (M, S)
    float M = NEGF, S = 0.f;
    for (int idx = t; idx < 1024; idx += 256) {
        float pm = swp[2 * idx], ps = swp[2 * idx + 1];
        float mn = fmaxf(M, pm);
        S = S * __expf(M - mn) + ps * __expf(pm - mn);
        M = mn;
    }
    for (int o = 32; o > 0; o >>= 1) {
        float m2 = __shfl_xor(M, o), s2 = __shfl_xor(S, o);
        float mn = fmaxf(M, m2);
        S = S * __expf(M - mn) + s2 * __expf(m2 - mn);
        M = mn;
    }
    if ((t & 63) == 0) { reds[0][t >> 6] = M; reds[1][t >> 6] = S; }
    __syncthreads();
    float Mf = fmaxf(fmaxf(reds[0][0], reds[0][1]), fmaxf(reds[0][2], reds[0][3]));
    float Sf = reds[1][0] * __expf(reds[0][0] - Mf) + reds[1][1] * __expf(reds[0][1] - Mf) +
               reds[1][2] * __expf(reds[0][2] - Mf) + reds[1][3] * __expf(reds[0][3] - Mf);
    float invS = 1.f / Sf;
    if (t < TN) {
        int n = n0 + t;
        aws[t] = (n < NDOCS) ? __expf(scoresv[n] - Mf) * invS : 0.f;
    }
    __syncthreads();
    for (int idx = t; idx < 514 * TN; idx += 256) {
        int j = idx >> 3, r = idx & 7;
        int n = n0 + r;
        float v = 0.f;
        if (n < NDOCS) {
            if (j < 256) v = h[(size_t)(1 + MD + n) * 256 + j];
            else if (j < 512) v = qhs[j - 256] * (aws[r] + 0.5f);
            else if (j == 512) v = cosv[n];
            else v = aws[r];
        }
        feats2[j][r] = v;
    }
    __syncthreads();
    float acc[TN];
    float bk = ldf(fusion_b, t, isbf);
#pragma unroll
    for (int r = 0; r < TN; r++) acc[r] = bk;
    const float4* fT4 = (const float4*)fwT;
    for (int j0 = 0; j0 < 512; j0 += 8) {          // 2 dwordx4 weight loads in flight
        float4 wa = fT4[(j0 >> 2) * 256 + t];
        float4 wb = fT4[((j0 >> 2) + 1) * 256 + t];
        float wv[8] = {wa.x, wa.y, wa.z, wa.w, wb.x, wb.y, wb.z, wb.w};
#pragma unroll
        for (int u = 0; u < 8; u++) {
            float4 fa = *(const float4*)&feats2[j0 + u][0];
            float4 fb = *(const float4*)&feats2[j0 + u][4];
            acc[0] = fmaf(fa.x, wv[u], acc[0]); acc[1] = fmaf(fa.y, wv[u], acc[1]);
            acc[2] = fmaf(fa.z, wv[u], acc[2]); acc[3] = fmaf(fa.w, wv[u], acc[3]);
            acc[4] = fmaf(fb.x, wv[u], acc[4]); acc[5] = fmaf(fb.y, wv[u], acc[5]);
            acc[6] = fmaf(fb.z, wv[u], acc[6]); acc[7] = fmaf(fb.w, wv[u], acc[7]);
        }
    }
    {                                              // tail j = 512, 513
        float4 wt = fT4[128 * 256 + t];
#pragma unroll
        for (int r = 0; r < TN; r++) acc[r] = fmaf(feats2[512][r], wt.x, acc[r]);
#pragma unroll
        for (int r = 0; r < TN; r++) acc[r] = fmaf(feats2[513][r], wt.y, acc[r]);
    }
    float ow = ldf(out_w, t, isbf);
    float outb = ldf(out_bp, 0, isbf);
#pragma unroll
    for (int r = 0; r < TN; r++) {
        float o = fmaxf(acc[r], 0.f) * ow;
        for (int off = 32; off > 0; off >>= 1) o += __shfl_down(o, off);
        if ((t & 63) == 0) red[r][t >> 6] = o;
    }
    __syncthreads();
    if (t < TN) {
        int n = n0 + t;
        if (n < NDOCS) {
            float o = red[t][0] + red[t][1] + red[t][2] + red[t][3] + outb + 0.5f * cosv[n];
            if (isbf) ((bf16*)outv)[n] = __float2bfloat16(o);
            else      ((float*)outv)[n] = o;
        }
    }
}

extern "C" void kernel_launch(void* const* d_in, const int* in_sizes, int n_in,
                              void* d_out, int out_size, void* d_ws, size_t ws_size,
                              hipStream_t stream) {
    const void* emb      = d_in[0];
    const int*  adj      = (const int*)d_in[1];
    const void* proj_w   = d_in[3];
    const void* proj_b   = d_in[4];
    const void* ln_scale = d_in[5];
    const void* ln_bias  = d_in[6];
    const void* gat_W    = d_in[7];
    const void* gat_a    = d_in[8];
    const void* fusion_w = d_in[9];
    const void* fusion_b = d_in[10];
    const void* out_w    = d_in[11];
    const void* out_b    = d_in[12];

    unsigned long long* maskb = (unsigned long long*)d_ws;
    int* flag = (int*)((char*)d_ws + (size_t)4096 * 64 * 8);
    float* f = (float*)((char*)d_ws + (size_t)4096 * 64 * 8 + 256);
    float* h       = f; f += 4096 * 256;
    float* srcb    = f; f += 4 * 4096;
    unsigned* d12g = (unsigned*)f; f += 4 * 4096;
    unsigned* dmaxu = (unsigned*)f; f += 2048;             // 2 layers x 64 slots x 16
    float* projT   = f; f += EMB * 256;                    // 96 x [256 x float4]
    float* gatT    = f; f += 2 * 65536;                    // 2 x 64 x [256 x float4]
    float* fwT     = f; f += 129 * 1024;                   // 129 x [256 x float4]
    float* scoresv = f; f += 4096;
    float* cosv    = f; f += 4096;
    float* swpart  = f; f += 2048;                         // 1024 x (m,s) pairs
    float* qrowb   = f; f += 260;                          // qrow[256] + qn
    ushort_t* whswz = (ushort_t*)f; f += 4096 * 256 / 2;   // 2MB

    k_adjmask<<<dim3(512), dim3(256), 0, stream>>>(adj, maskb, (const uint16_t*)emb, flag,
                                                   dmaxu, proj_w, proj_b, gat_W, fusion_w,
                                                   projT, gatT, fwT, qrowb);
    for (int layer = 0; layer < 2; layer++) {
        k_lnwh<<<dim3(TOTAL / LR), dim3(512), 0, stream>>>(emb, proj_b, projT, h, gatT,
                                                           ln_scale, ln_bias, gat_a,
                                                           whswz, srcb, d12g,
                                                           dmaxu + layer * 1024, layer, flag,
                                                           qrowb);
        k_pv<<<dim3(TOTAL / TI), dim3(512), 0, stream>>>(whswz, srcb, dmaxu + layer * 1024,
                                                         d12g, maskb, h);
    }
    k_scores<<<dim3(256), dim3(256), 0, stream>>>(h, scoresv, cosv, swpart);
    k_fusion<<<dim3((NDOCS + TN - 1) / TN), dim3(256), 0, stream>>>(h, scoresv, swpart,
                                                                    cosv, fwT, fusion_b, out_w,
                                                                    out_b, (void*)d_out, flag);
}

// Round 8
// 317.001 us; speedup vs baseline: 1.1587x; 1.1587x over previous
//
#include <hip/hip_runtime.h>
#include <hip/hip_bf16.h>
#include <stdint.h>

#define TOTAL 4096
#define EMB 384
#define MD 32
#define NDOCS (TOTAL - 1 - MD)   // 4063
#define LN_EPS 1e-5f
#define NEGF (-1e30f)

typedef __hip_bfloat16 bf16;
typedef unsigned short ushort_t;
typedef __attribute__((ext_vector_type(8))) short short8;
typedef __attribute__((ext_vector_type(4))) float f32x4;
typedef __attribute__((ext_vector_type(2))) float f32x2;

// Dual-dtype load: inputs may be stored bf16 or fp32; isbf selects at runtime.
__device__ __forceinline__ float ldf(const void* p, int i, int isbf) {
    return isbf ? __bfloat162float(((const bf16*)p)[i]) : ((const float*)p)[i];
}

// round-half-up f32 -> bf16 bits
__device__ __forceinline__ unsigned f2bf(float x) {
    return (__float_as_uint(x) + 0x8000u) >> 16;
}

// order-preserving float<->uint for atomicMax over signed floats
__device__ __forceinline__ unsigned fenc(float f) {
    unsigned u = __float_as_uint(f);
    return (u >> 31) ? ~u : (u | 0x80000000u);
}
__device__ __forceinline__ float fdec(unsigned k) {
    return __uint_as_float((k & 0x80000000u) ? (k & 0x7FFFFFFFu) : ~k);
}

// ---------------- adj -> bitmask; + dtype detect + dmax init + weight transpose -------
// R7 lesson: the kernel was STRAGGLER-bound since R6 — one block running a 384-step
// sequential uncoalesced q-row projection (~60-100us critical path), not dispatch-
// rate-bound (512 blocks made it worse). Now: 4096 blocks x 1 adj row (the shape that
// ran <40us in R1-R5) with int4 loads (1KB/wave-load, 4 independent in flight) and
// shfl-OR mask assembly; block 4096 does ONLY the q-row with float4/uint4 row loads
// (unroll 8 -> ~12 latency waves ~3us). Transpose reads are source-linear (coalesced).
// Weights packed float4-per-column: T[(d>>2)*1024 + c*4 + (d&3)].
#define TRTOT (EMB * 256 + 2 * 65536 + 514 * 256)   // 360960 transpose elements
__global__ __launch_bounds__(256) void k_adjmask(
        const int* adj, unsigned long long* maskb,
        const uint16_t* embp, int* flag, unsigned* dmaxu,
        const void* proj_w, const void* proj_b, const void* gat_W,
        const void* fusion_w,
        float* projT, float* gatT, float* fwT, float* qrow) {
    __shared__ int red[4];
    __shared__ float qred2[4];
    __shared__ float embs[EMB];
    int bid = blockIdx.x, t = threadIdx.x;
    int w = t >> 6, l = t & 63;
    // ---- dtype detect (every block, deterministic) ----
    int cnt = 0;
    for (int k = t; k < 4096; k += 256) {
        uint16_t wd = embp[2 * k];
        int e = (wd >> 7) & 0xFF;
        if (e >= 100 && e <= 140) cnt++;
    }
    for (int o = 32; o > 0; o >>= 1) cnt += __shfl_down(cnt, o);
    if ((t & 63) == 0) red[t >> 6] = cnt;
    __syncthreads();
    int isbf = (red[0] + red[1] + red[2] + red[3] > 2048) ? 1 : 0;
    if (bid == 0 && t == 0) flag[0] = isbf;
    if (bid < 4096) {
        // ---- one adj row -> 64 mask words, int4 loads + shfl-OR assembly ----
        const int4* adj4 = (const int4*)(adj + (size_t)bid * TOTAL);
        unsigned long long parts[4];
#pragma unroll
        for (int it = 0; it < 4; it++) {
            int4 a = adj4[it * 256 + t];           // columns (it*256+t)*4 .. +3
            unsigned nib = (a.x != 0 ? 1u : 0u) | (a.y != 0 ? 2u : 0u) |
                           (a.z != 0 ? 4u : 0u) | (a.w != 0 ? 8u : 0u);
            parts[it] = (unsigned long long)nib << (4 * (l & 15));
        }
#pragma unroll
        for (int it = 0; it < 4; it++) {
            unsigned long long m = parts[it];
            m |= __shfl_xor(m, 1);
            m |= __shfl_xor(m, 2);
            m |= __shfl_xor(m, 4);
            m |= __shfl_xor(m, 8);
            if ((l & 15) == 0)
                maskb[bid * 64 + it * 16 + w * 4 + (l >> 4)] = m;
        }
        if (bid == 0) {                            // init 2 layers x 64 slots x 16
            for (int idx = t; idx < 2048; idx += 256) dmaxu[idx] = 0x007FFFFFu;
        }
        // ---- weight transpose: source-linear (coalesced reads) ----
        int idx = bid * 256 + t;
        if (idx < EMB * 256) {                     // proj_w[c][d], s = c*384+d
            int c = idx / EMB, d = idx - c * EMB;
            projT[(d >> 2) * 1024 + c * 4 + (d & 3)] = ldf(proj_w, idx, isbf);
        } else if (idx < EMB * 256 + 2 * 65536) {  // gat_W source-linear
            int r = idx - EMB * 256;
            int ll = r >> 16, rem = r & 65535;
            int c = rem >> 8, d = rem & 255;
            gatT[ll * 65536 + (d >> 2) * 1024 + c * 4 + (d & 3)] = ldf(gat_W, r, isbf);
        } else if (idx < TRTOT) {                  // fusion_w[c][j], r = c*514+j
            int r = idx - (EMB * 256 + 2 * 65536);
            int c = r / 514, j = r - c * 514;
            fwT[(j >> 2) * 1024 + c * 4 + (j & 3)] = ldf(fusion_w, r, isbf);
        }
    } else {
        // ---- dedicated q-row block: qrow[t] = relu(b[t] + emb[0,:] . proj_w[t,:]) ----
        for (int d = t; d < EMB; d += 256) embs[d] = ldf((const void*)embp, d, isbf);
        __syncthreads();
        float p0 = 0.f, p1 = 0.f, p2 = 0.f, p3 = 0.f;   // chain j <- d%4 (R7 order)
        if (!isbf) {
            const float4* W4 = (const float4*)proj_w;
#pragma unroll 8
            for (int k = 0; k < 96; k++) {
                float4 wv = W4[t * 96 + k];
                float4 e = *(const float4*)&embs[k * 4];
                p0 = fmaf(e.x, wv.x, p0); p1 = fmaf(e.y, wv.y, p1);
                p2 = fmaf(e.z, wv.z, p2); p3 = fmaf(e.w, wv.w, p3);
            }
        } else {
            const uint4* W4 = (const uint4*)proj_w;
#pragma unroll 8
            for (int k = 0; k < 48; k++) {
                uint4 raw = W4[t * 48 + k];
                unsigned rws[4] = {raw.x, raw.y, raw.z, raw.w};
#pragma unroll
                for (int q = 0; q < 4; q++) {      // d = k*8 + 2q (+1); d%4 selects chain
                    float we = __uint_as_float(rws[q] << 16);
                    float wo = __uint_as_float(rws[q] & 0xFFFF0000u);
                    if ((q & 1) == 0) {
                        p0 = fmaf(embs[k * 8 + 2 * q], we, p0);
                        p1 = fmaf(embs[k * 8 + 2 * q + 1], wo, p1);
                    } else {
                        p2 = fmaf(embs[k * 8 + 2 * q], we, p2);
                        p3 = fmaf(embs[k * 8 + 2 * q + 1], wo, p3);
                    }
                }
            }
        }
        float accq = (p0 + p2) + (p1 + p3);
        float qv = fmaxf(accq + ldf(proj_b, t, isbf), 0.f);
        qrow[t] = qv;
        float a = qv * qv;
        for (int o = 32; o > 0; o >>= 1) a += __shfl_down(a, o);
        if ((t & 63) == 0) qred2[t >> 6] = a;
        __syncthreads();
        if (t == 0) qrow[256] = sqrtf(qred2[0] + qred2[1] + qred2[2] + qred2[3]) + 1e-8f;
    }
}

// ---------------- [proj+cos | read h] + LN + Wh GEMM + src/dst, 512 threads -----------
// Mapping (R5→R6): wave w8 = row owner (8 waves = 8 rows) AND d-split group;
// lane l = col-within-head; thread owns 4 cols {l, l+64, l+128, l+192}. Each
// broadcast x-read feeds 16 FMAs; weights stream once per block. Split-K partials
// exchanged via xpart (b32 stride-1, conflict-free), reduced in 2 passes of 4 rows.
// Row==wave makes cos/LN/src/dst reductions wave-local.
#define LR 8
__global__ __launch_bounds__(512) void k_lnwh(
        const void* emb, const void* proj_b, const float* projT,
        float* h, const float* gatT, const void* ln_scale, const void* ln_bias,
        const void* gat_a, ushort_t* whswz, float* srcb, unsigned* d12g,
        unsigned* dmaxu, int layer, const int* flagp, const float* qrow) {
    __shared__ float embs[8][EMB];          // 12KB (layer 0 only)
    __shared__ float xs[8][256];            // 8KB
    __shared__ float xpart[8][4][256];      // 32KB split-K partials (2-pass reuse)
    int isbf = flagp[0];
    int t5 = threadIdx.x;
    int w8 = t5 >> 6;                       // wave = row = d-group
    int l = t5 & 63;                        // lane = col-within-head
    int i0 = blockIdx.x * LR;
    int myrow = i0 + w8;
    float hv[4];
    if (layer == 0) {
        for (int idx = t5; idx < 8 * EMB; idx += 512) {
            int r = idx / EMB, d = idx % EMB;
            embs[r][d] = ldf(emb, (i0 + r) * EMB + d, isbf);
        }
        __syncthreads();
        // ---- proj producer: k4 in [w8*12, w8*12+12), 8 rows x 4 cols ----
        const float4* pT4 = (const float4*)projT;
        float ap[8][4];
#pragma unroll
        for (int r = 0; r < 8; r++)
#pragma unroll
            for (int cc = 0; cc < 4; cc++) ap[r][cc] = 0.f;
        for (int s = 0; s < 12; s++) {
            int k4 = w8 * 12 + s;
            float4 wv[4];
#pragma unroll
            for (int cc = 0; cc < 4; cc++) wv[cc] = pT4[k4 * 256 + cc * 64 + l];
#pragma unroll
            for (int r = 0; r < 8; r++) {
                float4 x = *(const float4*)&embs[r][k4 * 4];
#pragma unroll
                for (int cc = 0; cc < 4; cc++) {
                    ap[r][cc] = fmaf(x.x, wv[cc].x, ap[r][cc]);
                    ap[r][cc] = fmaf(x.y, wv[cc].y, ap[r][cc]);
                    ap[r][cc] = fmaf(x.z, wv[cc].z, ap[r][cc]);
                    ap[r][cc] = fmaf(x.w, wv[cc].w, ap[r][cc]);
                }
            }
        }
        // ---- split-K reduce, 2 passes of 4 rows ----
#pragma unroll
        for (int r = 0; r < 4; r++)
#pragma unroll
            for (int cc = 0; cc < 4; cc++) xpart[w8][r][cc * 64 + l] = ap[r][cc];
        __syncthreads();
        float bias[4];
#pragma unroll
        for (int cc = 0; cc < 4; cc++) bias[cc] = ldf(proj_b, cc * 64 + l, isbf);
        if (w8 < 4) {
#pragma unroll
            for (int cc = 0; cc < 4; cc++) {
                float s = 0.f;
#pragma unroll
                for (int g = 0; g < 8; g++) s += xpart[g][w8][cc * 64 + l];
                hv[cc] = fmaxf(s + bias[cc], 0.f);
            }
        }
        __syncthreads();
#pragma unroll
        for (int r = 4; r < 8; r++)
#pragma unroll
            for (int cc = 0; cc < 4; cc++) xpart[w8][r - 4][cc * 64 + l] = ap[r][cc];
        __syncthreads();
        if (w8 >= 4) {
#pragma unroll
            for (int cc = 0; cc < 4; cc++) {
                float s = 0.f;
#pragma unroll
                for (int g = 0; g < 8; g++) s += xpart[g][w8 - 4][cc * 64 + l];
                hv[cc] = fmaxf(s + bias[cc], 0.f);
            }
        }
        // ---- cos-update (qrow precomputed): s += 0.8*cos(q,s)*q, doc rows only ----
        if (myrow >= 1 + MD) {
            float qv[4];
#pragma unroll
            for (int cc = 0; cc < 4; cc++) qv[cc] = qrow[cc * 64 + l];
            float b = 0.f, c = 0.f;
#pragma unroll
            for (int cc = 0; cc < 4; cc++) {
                b = fmaf(hv[cc], hv[cc], b);
                c = fmaf(qv[cc], hv[cc], c);
            }
            for (int o = 32; o > 0; o >>= 1) { b += __shfl_xor(b, o); c += __shfl_xor(c, o); }
            float qn = qrow[256];
            float k = 0.8f * (c / (qn * (sqrtf(b) + 1e-8f)));
#pragma unroll
            for (int cc = 0; cc < 4; cc++) hv[cc] += k * qv[cc];
        }
#pragma unroll
        for (int cc = 0; cc < 4; cc++) h[(size_t)myrow * 256 + cc * 64 + l] = hv[cc];
    } else {
#pragma unroll
        for (int cc = 0; cc < 4; cc++) hv[cc] = h[(size_t)myrow * 256 + cc * 64 + l];
    }
    // ---- layernorm (wave-local: wave == row) ----
    {
        float a = 0.f, b2 = 0.f;
#pragma unroll
        for (int cc = 0; cc < 4; cc++) { a += hv[cc]; b2 = fmaf(hv[cc], hv[cc], b2); }
        for (int o = 32; o > 0; o >>= 1) { a += __shfl_xor(a, o); b2 += __shfl_xor(b2, o); }
        float mu = a * (1.f / 256.f);
        float var = b2 * (1.f / 256.f) - mu * mu;
        float rs = rsqrtf(var + LN_EPS);
#pragma unroll
        for (int cc = 0; cc < 4; cc++) {
            float sc = ldf(ln_scale, layer * 256 + cc * 64 + l, isbf);
            float lb = ldf(ln_bias, layer * 256 + cc * 64 + l, isbf);
            xs[w8][cc * 64 + l] = (hv[cc] - mu) * rs * sc + lb;
        }
    }
    __syncthreads();
    // ---- Wh producer: k4 in [w8*8, w8*8+8) ----
    const float4* gT4 = (const float4*)(gatT + layer * 65536);
    float aw[8][4];
#pragma unroll
    for (int r = 0; r < 8; r++)
#pragma unroll
        for (int cc = 0; cc < 4; cc++) aw[r][cc] = 0.f;
    for (int s = 0; s < 8; s++) {
        int k4 = w8 * 8 + s;
        float4 wv[4];
#pragma unroll
        for (int cc = 0; cc < 4; cc++) wv[cc] = gT4[k4 * 256 + cc * 64 + l];
#pragma unroll
        for (int r = 0; r < 8; r++) {
            float4 x = *(const float4*)&xs[r][k4 * 4];
#pragma unroll
            for (int cc = 0; cc < 4; cc++) {
                aw[r][cc] = fmaf(x.x, wv[cc].x, aw[r][cc]);
                aw[r][cc] = fmaf(x.y, wv[cc].y, aw[r][cc]);
                aw[r][cc] = fmaf(x.z, wv[cc].z, aw[r][cc]);
                aw[r][cc] = fmaf(x.w, wv[cc].w, aw[r][cc]);
            }
        }
    }
#pragma unroll
    for (int r = 0; r < 4; r++)
#pragma unroll
        for (int cc = 0; cc < 4; cc++) xpart[w8][r][cc * 64 + l] = aw[r][cc];
    __syncthreads();
    float acc2[4];
    if (w8 < 4) {
#pragma unroll
        for (int cc = 0; cc < 4; cc++) {
            float s = 0.f;
#pragma unroll
            for (int g = 0; g < 8; g++) s += xpart[g][w8][cc * 64 + l];
            acc2[cc] = s;
        }
    }
    __syncthreads();
#pragma unroll
    for (int r = 4; r < 8; r++)
#pragma unroll
        for (int cc = 0; cc < 4; cc++) xpart[w8][r - 4][cc * 64 + l] = aw[r][cc];
    __syncthreads();
    if (w8 >= 4) {
#pragma unroll
        for (int cc = 0; cc < 4; cc++) {
            float s = 0.f;
#pragma unroll
            for (int g = 0; g < 8; g++) s += xpart[g][w8 - 4][cc * 64 + l];
            acc2[cc] = s;
        }
    }
    // ---- whswz store + src/dst reductions + dmax (col cc*64+l == head cc, lane l) ----
#pragma unroll
    for (int cc = 0; cc < 4; cc++) {
        int col = cc * 64 + l;
        int off = (myrow >> 6) * 16384 + (col >> 6) * 4096 + ((myrow >> 3) & 7) * 512 +
                  ((col >> 4) & 3) * 128 + (col & 15) * 8 + (myrow & 7);
        whswz[off] = (ushort_t)f2bf(acc2[cc]);
    }
    float sv[4], dv[4];
#pragma unroll
    for (int cc = 0; cc < 4; cc++) {
        float av1 = ldf(gat_a, layer * 512 + cc * 128 + l, isbf);
        float av2 = ldf(gat_a, layer * 512 + cc * 128 + 64 + l, isbf);
        sv[cc] = acc2[cc] * av1;
        dv[cc] = acc2[cc] * av2;
    }
    for (int o = 32; o > 0; o >>= 1) {
#pragma unroll
        for (int cc = 0; cc < 4; cc++) {
            sv[cc] += __shfl_down(sv[cc], o);
            dv[cc] += __shfl_down(dv[cc], o);
        }
    }
    if (l == 0) {
        const float LOG2E = 1.44269504f;
#pragma unroll
        for (int cc = 0; cc < 4; cc++) {
            srcb[cc * 4096 + myrow] = sv[cc];
            float D1 = exp2f(dv[cc] * LOG2E), D2 = exp2f(0.2f * dv[cc] * LOG2E);
            d12g[cc * 4096 + myrow] = (f2bf(D2) << 16) | f2bf(D1);
            atomicMax(&dmaxu[(blockIdx.x & 63) * 16 + cc], fenc(dv[cc]));
        }
    }
}

// ---------------- PV via MFMA, full-j accumulation + FUSED epilogue -------------------
#define TI 16
__global__ __launch_bounds__(512) void k_pv(const ushort_t* whswz, const float* srcb,
                                            const unsigned* dmaxu, const unsigned* d12g,
                                            const unsigned long long* maskb, float* h) {
    __shared__ unsigned long long mbs[16 * 66];            // masks: 16 rows x 64 words
    __shared__ __align__(16) f32x4 accsh[16 * 64];         // 16KB cross-kq reduce
    __shared__ __align__(16) float lsh[4][4][4];           // [head][quad][rr] kq1 rowsums
    __shared__ float srcs[64];
    __shared__ float dmx[4];
    __shared__ unsigned mlut[4];
    int t = threadIdx.x;
    int W = t >> 6, lane = t & 63;
    int hH = W & 3, kq = W >> 2;
    int quad = lane >> 4, c16 = lane & 15;
    int i0 = blockIdx.x * TI;
    if (t < 4) mlut[t] = (t & 1 ? 0x0000FFFFu : 0u) | (t & 2 ? 0xFFFF0000u : 0u);
    if (t < 256) {                                 // wave w reduces head w's 64 dmax slots
        int hh = t >> 6, sl = t & 63;
        float v = fdec(dmaxu[sl * 16 + hh]);
        for (int o = 32; o > 0; o >>= 1) v = fmaxf(v, __shfl_xor(v, o));
        if (sl == 0) dmx[hh] = v;
    }
    for (int idx = t; idx < 16 * 64; idx += 512) {
        int r = idx >> 6, wd = idx & 63;
        mbs[r * 66 + wd] = maskb[(size_t)(i0 + r) * 64 + wd];
    }
    if (t < 64) srcs[t] = srcb[(t >> 4) * 4096 + i0 + (t & 15)];
    __syncthreads();
    const float LOG2E = 1.44269504f;
    float dm = dmx[hH];
    float src = srcs[hH * 16 + c16];
    float sd = src + dm;
    float rce = -fmaxf(sd, 0.2f * sd);             // -mhat >= true masked max
    float E1 = exp2f((src + rce) * LOG2E);
    float E2 = exp2f((0.2f * src + rce) * LOG2E);
    f32x4 acc[4];
    f32x4 accl = (f32x4){0.f, 0.f, 0.f, 0.f};
#pragma unroll
    for (int ct = 0; ct < 4; ct++) acc[ct] = (f32x4){0.f, 0.f, 0.f, 0.f};
    uint4 onesu;                                   // B ones-column frag (col c16==0)
    unsigned os = (c16 == 0) ? 0x3F803F80u : 0u;
    onesu.x = os; onesu.y = os; onesu.z = os; onesu.w = os;
    short8 bfones = __builtin_bit_cast(short8, onesu);
    const uint4* g4 = (const uint4*)whswz;
    const uint4* d4 = (const uint4*)d12g;
    size_t b0 = (size_t)hH * 512 + (size_t)(kq * 4 + quad) * 64 + c16;
    int dbase = hH * 1024, d0i = kq * 8 + quad * 2;   // uint4 units
    uint4 bA0 = g4[b0],        bA1 = g4[b0 + 16],        bA2 = g4[b0 + 32],        bA3 = g4[b0 + 48];
    uint4 bB0 = g4[b0 + 2048], bB1 = g4[b0 + 2048 + 16], bB2 = g4[b0 + 2048 + 32], bB3 = g4[b0 + 2048 + 48];
    uint4 dA0 = d4[dbase + d0i],      dA1 = d4[dbase + d0i + 1];
    uint4 dB0 = d4[dbase + 16 + d0i], dB1 = d4[dbase + 16 + d0i + 1];
    auto pvstep = [&](uint4& B0, uint4& B1, uint4& B2, uint4& B3,
                      uint4& DD0, uint4& DD1, int s) {
        uint4 bc0 = B0, bc1 = B1, bc2 = B2, bc3 = B3;
        uint4 dc0 = DD0, dc1 = DD1;
        if (s < 62) {                              // refill this slot with step s+2
            size_t bs = b0 + (size_t)(s + 2) * 2048;
            B0 = g4[bs]; B1 = g4[bs + 16]; B2 = g4[bs + 32]; B3 = g4[bs + 48];
            int di = dbase + (s + 2) * 16 + d0i;
            DD0 = d4[di]; DD1 = d4[di + 1];
        }
        unsigned mby = (unsigned)(mbs[c16 * 66 + s] >> (kq * 32 + quad * 8)) & 0xFFu;
        unsigned dw[8] = {dc0.x, dc0.y, dc0.z, dc0.w, dc1.x, dc1.y, dc1.z, dc1.w};
        unsigned pu[4];
#pragma unroll
        for (int q = 0; q < 4; q++) {
            unsigned a = dw[2 * q], b = dw[2 * q + 1];
            f32x2 D1 = (f32x2){__uint_as_float(a << 16), __uint_as_float(b << 16)};
            f32x2 D2 = (f32x2){__uint_as_float(a & 0xFFFF0000u), __uint_as_float(b & 0xFFFF0000u)};
            f32x2 v1 = D1 * E1;
            f32x2 v2 = D2 * E2;
            f32x2 m = __builtin_elementwise_max(v1, v2);
            unsigned v = ((__float_as_uint(m.x) + 0x8000u) >> 16) |
                         ((__float_as_uint(m.y) + 0x8000u) & 0xFFFF0000u);
            pu[q] = v & mlut[(mby >> (2 * q)) & 3u];
        }
        uint4 afu;
        afu.x = pu[0]; afu.y = pu[1]; afu.z = pu[2]; afu.w = pu[3];
        short8 af = __builtin_bit_cast(short8, afu);
        acc[0] = __builtin_amdgcn_mfma_f32_16x16x32_bf16(af, __builtin_bit_cast(short8, bc0), acc[0], 0, 0, 0);
        acc[1] = __builtin_amdgcn_mfma_f32_16x16x32_bf16(af, __builtin_bit_cast(short8, bc1), acc[1], 0, 0, 0);
        acc[2] = __builtin_amdgcn_mfma_f32_16x16x32_bf16(af, __builtin_bit_cast(short8, bc2), acc[2], 0, 0, 0);
        acc[3] = __builtin_amdgcn_mfma_f32_16x16x32_bf16(af, __builtin_bit_cast(short8, bc3), acc[3], 0, 0, 0);
        accl = __builtin_amdgcn_mfma_f32_16x16x32_bf16(af, bfones, accl, 0, 0, 0);
    };
    for (int sp = 0; sp < 32; sp++) {
        pvstep(bA0, bA1, bA2, bA3, dA0, dA1, 2 * sp);
        pvstep(bB0, bB1, bB2, bB3, dB0, dB1, 2 * sp + 1);
    }
    __syncthreads();
    if (kq == 1) {
#pragma unroll
        for (int ct = 0; ct < 4; ct++)
            accsh[(hH * 4 + ct) * 64 + lane] = acc[ct];
        if (c16 == 0) *(f32x4*)&lsh[hH][quad][0] = accl;
    }
    __syncthreads();
    if (kq == 0) {
        float ls[4];
#pragma unroll
        for (int rr = 0; rr < 4; rr++)
            ls[rr] = __shfl(accl[rr], quad * 16) + lsh[hH][quad][rr];
#pragma unroll
        for (int ct = 0; ct < 4; ct++) {
            f32x4 o = acc[ct] + accsh[(hH * 4 + ct) * 64 + lane];
#pragma unroll
            for (int rr = 0; rr < 4; rr++) {       // D: col=lane&15, row=quad*4+rr
                int row = i0 + quad * 4 + rr;
                size_t idx = (size_t)row * 256 + hH * 64 + ct * 16 + c16;
                float hn = 0.5f * fmaxf(o[rr] / ls[rr], 0.f) + 0.5f * h[idx];
                h[idx] = hn;
            }
        }
    }
}

// ---------------- scores + cos from final h (wave-per-row) ----------------------------
__global__ __launch_bounds__(256) void k_scores(const float* h, float* scoresv, float* cosv,
                                                float* swp) {
    int t = threadIdx.x, W = t >> 6, lane = t & 63;
    const float4* h4 = (const float4*)h;
    int gw = blockIdx.x * 4 + W;
    float4 q4 = h4[lane];                          // final q row
    float a = q4.x * q4.x + q4.y * q4.y + q4.z * q4.z + q4.w * q4.w;
    for (int o = 32; o > 0; o >>= 1) a += __shfl_xor(a, o);
    float qn = sqrtf(a) + 1e-8f;
    float mw = NEGF, sw = 0.f;
    for (int n = gw; n < NDOCS; n += 1024) {
        float4 s4 = h4[(size_t)(1 + MD + n) * 64 + lane];
        float b = s4.x * s4.x + s4.y * s4.y + s4.z * s4.z + s4.w * s4.w;
        float c = q4.x * s4.x + q4.y * s4.y + q4.z * s4.z + q4.w * s4.w;
        for (int o = 32; o > 0; o >>= 1) { b += __shfl_xor(b, o); c += __shfl_xor(c, o); }
        float sc = c * (1.f / 16.f);               // wave-uniform (full butterfly)
        if (lane == 0) {
            scoresv[n] = sc;
            cosv[n] = c / (qn * (sqrtf(b) + 1e-8f));
        }
        float mn = fmaxf(mw, sc);
        sw = sw * __expf(mw - mn) + __expf(sc - mn);
        mw = mn;
    }
    if (lane == 0) { swp[2 * gw] = mw; swp[2 * gw + 1] = sw; }
}

// ---------------- fused softmax-reduce + feature GEMM + output ------------------------
#define TN 8
__global__ __launch_bounds__(256) void k_fusion(const float* h,
                                                const float* scoresv, const float* swp,
                                                const float* cosv,
                                                const float* fwT, const void* fusion_b,
                                                const void* out_w, const void* out_bp,
                                                void* outv, const int* flagp) {
    __shared__ float feats2[514][TN];
    __shared__ float qhs[256];
    __shared__ float red[TN][4];
    __shared__ float reds[2][4];
    __shared__ float aws[TN];
    int isbf = flagp[0];
    int t = threadIdx.x;
    int n0 = blockIdx.x * TN;
    qhs[t] = h[t];                                 // final q row
    // reduce the 1024 per-wave online-softmax partials -> global (M, S)
    float M = NEGF, S = 0.f;
    for (int idx = t; idx < 1024; idx += 256) {
        float pm = swp[2 * idx], ps = swp[2 * idx + 1];
        float mn = fmaxf(M, pm);
        S = S * __expf(M - mn) + ps * __expf(pm - mn);
        M = mn;
    }
    for (int o = 32; o > 0; o >>= 1) {
        float m2 = __shfl_xor(M, o), s2 = __shfl_xor(S, o);
        float mn = fmaxf(M, m2);
        S = S * __expf(M - mn) + s2 * __expf(m2 - mn);
        M = mn;
    }
    if ((t & 63) == 0) { reds[0][t >> 6] = M; reds[1][t >> 6] = S; }
    __syncthreads();
    float Mf = fmaxf(fmaxf(reds[0][0], reds[0][1]), fmaxf(reds[0][2], reds[0][3]));
    float Sf = reds[1][0] * __expf(reds[0][0] - Mf) + reds[1][1] * __expf(reds[0][1] - Mf) +
               reds[1][2] * __expf(reds[0][2] - Mf) + reds[1][3] * __expf(reds[0][3] - Mf);
    float invS = 1.f / Sf;
    if (t < TN) {
        int n = n0 + t;
        aws[t] = (n < NDOCS) ? __expf(scoresv[n] - Mf) * invS : 0.f;
    }
    __syncthreads();
    for (int idx = t; idx < 514 * TN; idx += 256) {
        int j = idx >> 3, r = idx & 7;
        int n = n0 + r;
        float v = 0.f;
        if (n < NDOCS) {
            if (j < 256) v = h[(size_t)(1 + MD + n) * 256 + j];
            else if (j < 512) v = qhs[j - 256] * (aws[r] + 0.5f);
            else if (j == 512) v = cosv[n];
            else v = aws[r];
        }
        feats2[j][r] = v;
    }
    __syncthreads();
    float acc[TN];
    float bk = ldf(fusion_b, t, isbf);
#pragma unroll
    for (int r = 0; r < TN; r++) acc[r] = bk;
    const float4* fT4 = (const float4*)fwT;
    for (int j0 = 0; j0 < 512; j0 += 8) {          // 2 dwordx4 weight loads in flight
        float4 wa = fT4[(j0 >> 2) * 256 + t];
        float4 wb = fT4[((j0 >> 2) + 1) * 256 + t];
        float wv[8] = {wa.x, wa.y, wa.z, wa.w, wb.x, wb.y, wb.z, wb.w};
#pragma unroll
        for (int u = 0; u < 8; u++) {
            float4 fa = *(const float4*)&feats2[j0 + u][0];
            float4 fb = *(const float4*)&feats2[j0 + u][4];
            acc[0] = fmaf(fa.x, wv[u], acc[0]); acc[1] = fmaf(fa.y, wv[u], acc[1]);
            acc[2] = fmaf(fa.z, wv[u], acc[2]); acc[3] = fmaf(fa.w, wv[u], acc[3]);
            acc[4] = fmaf(fb.x, wv[u], acc[4]); acc[5] = fmaf(fb.y, wv[u], acc[5]);
            acc[6] = fmaf(fb.z, wv[u], acc[6]); acc[7] = fmaf(fb.w, wv[u], acc[7]);
        }
    }
    {                                              // tail j = 512, 513
        float4 wt = fT4[128 * 256 + t];
#pragma unroll
        for (int r = 0; r < TN; r++) acc[r] = fmaf(feats2[512][r], wt.x, acc[r]);
#pragma unroll
        for (int r = 0; r < TN; r++) acc[r] = fmaf(feats2[513][r], wt.y, acc[r]);
    }
    float ow = ldf(out_w, t, isbf);
    float outb = ldf(out_bp, 0, isbf);
#pragma unroll
    for (int r = 0; r < TN; r++) {
        float o = fmaxf(acc[r], 0.f) * ow;
        for (int off = 32; off > 0; off >>= 1) o += __shfl_down(o, off);
        if ((t & 63) == 0) red[r][t >> 6] = o;
    }
    __syncthreads();
    if (t < TN) {
        int n = n0 + t;
        if (n < NDOCS) {
            float o = red[t][0] + red[t][1] + red[t][2] + red[t][3] + outb + 0.5f * cosv[n];
            if (isbf) ((bf16*)outv)[n] = __float2bfloat16(o);
            else      ((float*)outv)[n] = o;
        }
    }
}

extern "C" void kernel_launch(void* const* d_in, const int* in_sizes, int n_in,
                              void* d_out, int out_size, void* d_ws, size_t ws_size,
                              hipStream_t stream) {
    const void* emb      = d_in[0];
    const int*  adj      = (const int*)d_in[1];
    const void* proj_w   = d_in[3];
    const void* proj_b   = d_in[4];
    const void* ln_scale = d_in[5];
    const void* ln_bias  = d_in[6];
    const void* gat_W    = d_in[7];
    const void* gat_a    = d_in[8];
    const void* fusion_w = d_in[9];
    const void* fusion_b = d_in[10];
    const void* out_w    = d_in[11];
    const void* out_b    = d_in[12];

    unsigned long long* maskb = (unsigned long long*)d_ws;
    int* flag = (int*)((char*)d_ws + (size_t)4096 * 64 * 8);
    float* f = (float*)((char*)d_ws + (size_t)4096 * 64 * 8 + 256);
    float* h       = f; f += 4096 * 256;
    float* srcb    = f; f += 4 * 4096;
    unsigned* d12g = (unsigned*)f; f += 4 * 4096;
    unsigned* dmaxu = (unsigned*)f; f += 2048;             // 2 layers x 64 slots x 16
    float* projT   = f; f += EMB * 256;                    // 96 x [256 x float4]
    float* gatT    = f; f += 2 * 65536;                    // 2 x 64 x [256 x float4]
    float* fwT     = f; f += 129 * 1024;                   // 129 x [256 x float4]
    float* scoresv = f; f += 4096;
    float* cosv    = f; f += 4096;
    float* swpart  = f; f += 2048;                         // 1024 x (m,s) pairs
    float* qrowb   = f; f += 260;                          // qrow[256] + qn
    ushort_t* whswz = (ushort_t*)f; f += 4096 * 256 / 2;   // 2MB

    k_adjmask<<<dim3(4097), dim3(256), 0, stream>>>(adj, maskb, (const uint16_t*)emb, flag,
                                                    dmaxu, proj_w, proj_b, gat_W, fusion_w,
                                                    projT, gatT, fwT, qrowb);
    for (int layer = 0; layer < 2; layer++) {
        k_lnwh<<<dim3(TOTAL / LR), dim3(512), 0, stream>>>(emb, proj_b, projT, h, gatT,
                                                           ln_scale, ln_bias, gat_a,
                                                           whswz, srcb, d12g,
                                                           dmaxu + layer * 1024, layer, flag,
                                                           qrowb);
        k_pv<<<dim3(TOTAL / TI), dim3(512), 0, stream>>>(whswz, srcb, dmaxu + layer * 1024,
                                                         d12g, maskb, h);
    }
    k_scores<<<dim3(256), dim3(256), 0, stream>>>(h, scoresv, cosv, swpart);
    k_fusion<<<dim3((NDOCS + TN - 1) / TN), dim3(256), 0, stream>>>(h, scoresv, swpart,
                                                                    cosv, fwT, fusion_b, out_w,
                                                                    out_b, (void*)d_out, flag);
}